// Round 8
// baseline (94.503 us; speedup 1.0000x reference)
//
#include <hip/hip_runtime.h>

#define POOL 7
#define FM_H 128
#define FM_W 128
#define FM_C 512
#define NSTRIPE 8              // y-stripes of 16 rows = 4 MiB each -> 1 per XCD
#define CELLS_PER_BLK 16       // fallback kernel config

typedef float f32x4 __attribute__((ext_vector_type(4)));

// ---------- Pass 1: bin (roi,py) tasks by y0 stripe ----------
__global__ __launch_bounds__(256) void bin_kernel(
    const float* __restrict__ rois, int* __restrict__ count,
    int* __restrict__ list, int n_tasks, int cap)
{
    const int t = blockIdx.x * 256 + threadIdx.x;
    if (t >= n_tasks) return;
    const int r  = t / POOL;
    const int py = t - r * POOL;

    const float4 rv = *reinterpret_cast<const float4*>(rois + (size_t)r * 4);
    const int ymin = (int)rv.z;
    const int ymax = (int)rv.w;
    const int sy   = ymax - ymin;

    const float scy  = (float)sy / 7.0f;
    const float srcy = (float)py * scy;
    const int   iy0  = (int)floorf(srcy);
    const int   y0   = ymin + iy0;

    const int s   = y0 >> 4;                      // 16-row stripe -> XCD
    const int pos = atomicAdd(&count[s], 1);
    list[s * cap + pos] = t;
}

// ---------- Pass 2: pooled rows, stripe-pinned to XCDs ----------
// Block = one (roi,py) task: writes out[r][py][0..6][512] = 14 KB contiguous
// from ONE XCD (R4-R7 showed 256B-fragmented per-XCD writes cap us at
// ~5.4 TB/s mixed; contiguous per-XCD write runs are the untested lever).
// Corner reads stay inside the XCD's 4 MiB y-stripe (L2-resident).
__global__ __launch_bounds__(256) void pool_stripe_kernel(
    const float* __restrict__ fm,
    const float* __restrict__ rois,
    float* __restrict__ out,
    const int* __restrict__ count,
    const int* __restrict__ list,
    int cap)
{
    const int s = blockIdx.x & (NSTRIPE - 1);     // stripe -> XCD
    const int i = blockIdx.x >> 3;
    if (i >= count[s]) return;
    const int t  = list[s * cap + i];
    const int r  = t / POOL;
    const int py = t - r * POOL;

    const float4 rv = *reinterpret_cast<const float4*>(rois + (size_t)r * 4);
    const int xmin = (int)rv.x;
    const int xmax = (int)rv.y;
    const int ymin = (int)rv.z;
    const int ymax = (int)rv.w;
    const int sy = ymax - ymin;
    const int sx = xmax - xmin;

    // y coords: uniform for the whole block (reference-exact fp32 ops).
    const float scy  = (float)sy / 7.0f;
    const float srcy = (float)py * scy;
    const int   iy0  = (int)floorf(srcy);
    const int   iy1  = min(iy0 + 1, sy - 1);
    const float fy   = srcy - (float)iy0;
    const int   y0   = ymin + iy0;
    const int   y1   = ymin + iy1;

    const float scx = (float)sx / 7.0f;

    const int half = threadIdx.x >> 7;            // 2 px in flight per block
    const int lane = threadIdx.x & 127;           // 128 lanes x float4 = 512 ch
    const int c4   = lane << 2;

    const size_t rowy0 = (size_t)y0 * FM_W;
    const size_t rowy1 = (size_t)y1 * FM_W;
    const size_t obase = ((size_t)t) * POOL * FM_C;   // out[r][py][0][0]

    #pragma unroll
    for (int j = 0; j < 4; ++j) {
        const int px = j * 2 + half;
        if (px < POOL) {
            const float srcx = (float)px * scx;
            const int   ix0  = (int)floorf(srcx);
            const int   ix1  = min(ix0 + 1, sx - 1);
            const float fx   = srcx - (float)ix0;
            const int   x0   = xmin + ix0;
            const int   x1   = xmin + ix1;

            const float4 tl = *reinterpret_cast<const float4*>(fm + (rowy0 + x0) * FM_C + c4);
            const float4 tr = *reinterpret_cast<const float4*>(fm + (rowy0 + x1) * FM_C + c4);
            const float4 bl = *reinterpret_cast<const float4*>(fm + (rowy1 + x0) * FM_C + c4);
            const float4 br = *reinterpret_cast<const float4*>(fm + (rowy1 + x1) * FM_C + c4);

            f32x4 o;
            {
                float top, bot;
                top = tl.x + (tr.x - tl.x) * fx; bot = bl.x + (br.x - bl.x) * fx; o.x = top + (bot - top) * fy;
                top = tl.y + (tr.y - tl.y) * fx; bot = bl.y + (br.y - bl.y) * fx; o.y = top + (bot - top) * fy;
                top = tl.z + (tr.z - tl.z) * fx; bot = bl.z + (br.z - bl.z) * fx; o.z = top + (bot - top) * fy;
                top = tl.w + (tr.w - tl.w) * fx; bot = bl.w + (br.w - bl.w) * fx; o.w = top + (bot - top) * fy;
            }

            f32x4* dst = reinterpret_cast<f32x4*>(out + obase + (size_t)px * FM_C + c4);
            __builtin_nontemporal_store(o, dst);
        }
    }
}

// ---------- Fallback: proven R4 kernel (27.5us), used if ws too small ----------
__global__ __launch_bounds__(256) void roi_pool_fallback(
    const float* __restrict__ fm, const float* __restrict__ rois,
    float* __restrict__ out, int n_cells)
{
    const int tid  = threadIdx.x;
    const int g    = blockIdx.x & 7;
    const int cb   = blockIdx.x >> 3;
    const int cell = cb * CELLS_PER_BLK + (tid >> 4);
    if (cell >= n_cells) return;
    const int c4   = (g << 6) + ((tid & 15) << 2);

    const int r  = cell / (POOL * POOL);
    const int p  = cell - r * (POOL * POOL);
    const int py = p / POOL;
    const int px = p - py * POOL;

    const float4 rv = *reinterpret_cast<const float4*>(rois + (size_t)r * 4);
    const int xmin = (int)rv.x, xmax = (int)rv.y, ymin = (int)rv.z, ymax = (int)rv.w;
    const int sy = ymax - ymin, sx = xmax - xmin;

    const float scy = (float)sy / 7.0f, srcy = (float)py * scy;
    const int iy0 = (int)floorf(srcy), iy1 = min(iy0 + 1, sy - 1);
    const float fy = srcy - (float)iy0;
    const int y0 = ymin + iy0, y1 = ymin + iy1;

    const float scx = (float)sx / 7.0f, srcx = (float)px * scx;
    const int ix0 = (int)floorf(srcx), ix1 = min(ix0 + 1, sx - 1);
    const float fx = srcx - (float)ix0;
    const int x0 = xmin + ix0, x1 = xmin + ix1;

    const float4 tl = *reinterpret_cast<const float4*>(fm + ((size_t)(y0 * FM_W + x0)) * FM_C + c4);
    const float4 tr = *reinterpret_cast<const float4*>(fm + ((size_t)(y0 * FM_W + x1)) * FM_C + c4);
    const float4 bl = *reinterpret_cast<const float4*>(fm + ((size_t)(y1 * FM_W + x0)) * FM_C + c4);
    const float4 br = *reinterpret_cast<const float4*>(fm + ((size_t)(y1 * FM_W + x1)) * FM_C + c4);

    f32x4 o;
    float top, bot;
    top = tl.x + (tr.x - tl.x) * fx; bot = bl.x + (br.x - bl.x) * fx; o.x = top + (bot - top) * fy;
    top = tl.y + (tr.y - tl.y) * fx; bot = bl.y + (br.y - bl.y) * fx; o.y = top + (bot - top) * fy;
    top = tl.z + (tr.z - tl.z) * fx; bot = bl.z + (br.z - bl.z) * fx; o.z = top + (bot - top) * fy;
    top = tl.w + (tr.w - tl.w) * fx; bot = bl.w + (br.w - bl.w) * fx; o.w = top + (bot - top) * fy;

    f32x4* dst = reinterpret_cast<f32x4*>(out + (size_t)cell * FM_C + c4);
    __builtin_nontemporal_store(o, dst);
}

extern "C" void kernel_launch(void* const* d_in, const int* in_sizes, int n_in,
                              void* d_out, int out_size, void* d_ws, size_t ws_size,
                              hipStream_t stream) {
    const float* fm   = (const float*)d_in[0];
    const float* rois = (const float*)d_in[1];
    float* out        = (float*)d_out;

    const int R       = in_sizes[1] / 4;
    const int n_tasks = R * POOL;                 // 7168 (roi,py) rows
    const int cap     = n_tasks;                  // per-stripe worst case
    const size_t need = (size_t)NSTRIPE * 4 + (size_t)NSTRIPE * cap * 4;

    if (ws_size < need) {
        const int n_cells = R * POOL * POOL;
        const int cblocks = (n_cells + CELLS_PER_BLK - 1) / CELLS_PER_BLK;
        roi_pool_fallback<<<cblocks * 8, 256, 0, stream>>>(fm, rois, out, n_cells);
        return;
    }

    int* count = (int*)d_ws;                      // [8]
    int* list  = count + NSTRIPE;                 // [8][cap]

    hipMemsetAsync(count, 0, NSTRIPE * sizeof(int), stream);
    bin_kernel<<<(n_tasks + 255) / 256, 256, 0, stream>>>(rois, count, list, n_tasks, cap);
    pool_stripe_kernel<<<n_tasks * NSTRIPE, 256, 0, stream>>>(fm, rois, out, count, list, cap);
}

// Round 9
// 89.067 us; speedup vs baseline: 1.0610x; 1.0610x over previous
//
#include <hip/hip_runtime.h>

#define POOL 7
#define FM_H 128
#define FM_W 128
#define FM_C 512
#define NSTRIPE 8              // y-stripes of 16 rows = 4 MiB each -> 1 per XCD
#define BLK_PER_STRIPE 256     // 2048 persistent blocks total = 8/CU
#define CELLS_PER_BLK 16       // fallback kernel config

typedef float f32x4 __attribute__((ext_vector_type(4)));

// ---------- Pass 0: zero the 8 counters (hipMemsetAsync in-graph cost 60us in R8!) ----------
__global__ void zero_kernel(int* __restrict__ count) {
    if (threadIdx.x < NSTRIPE) count[threadIdx.x] = 0;
}

// ---------- Pass 1: bin (roi,py) tasks by y0 stripe ----------
__global__ __launch_bounds__(256) void bin_kernel(
    const float* __restrict__ rois, int* __restrict__ count,
    int* __restrict__ list, int n_tasks, int cap)
{
    const int t = blockIdx.x * 256 + threadIdx.x;
    if (t >= n_tasks) return;
    const int r  = t / POOL;
    const int py = t - r * POOL;

    const float4 rv = *reinterpret_cast<const float4*>(rois + (size_t)r * 4);
    const int ymin = (int)rv.z;
    const int ymax = (int)rv.w;
    const int sy   = ymax - ymin;

    const float scy  = (float)sy / 7.0f;
    const float srcy = (float)py * scy;
    const int   iy0  = (int)floorf(srcy);
    const int   y0   = ymin + iy0;

    const int s   = y0 >> 4;                      // 16-row stripe -> XCD
    const int pos = atomicAdd(&count[s], 1);
    list[s * cap + pos] = t;
}

// ---------- Pass 2: persistent, stripe-pinned pooled-row kernel ----------
// 256 blocks per stripe, stripe s -> XCD s (bid&7). Each block grid-strides
// its stripe's task list: one task = (roi,py) -> 14 KB contiguous NT write,
// 1 KB-contiguous corner reads per wave, reads confined to the XCD's 4 MiB
// y-stripe (L2-resident). Clean test of write/read-contiguity (R8 was
// contaminated by a 60us in-graph memset + 8x grid overprovision).
__global__ __launch_bounds__(256) void pool_stripe_kernel(
    const float* __restrict__ fm,
    const float* __restrict__ rois,
    float* __restrict__ out,
    const int* __restrict__ count,
    const int* __restrict__ list,
    int cap)
{
    const int s  = blockIdx.x & (NSTRIPE - 1);    // stripe -> XCD
    const int bb = blockIdx.x >> 3;               // 0..255 within stripe
    const int n  = count[s];

    const int half = threadIdx.x >> 7;            // 2 px in flight per block
    const int lane = threadIdx.x & 127;           // 128 lanes x float4 = 512 ch
    const int c4   = lane << 2;

    for (int i = bb; i < n; i += BLK_PER_STRIPE) {
        const int t  = list[s * cap + i];
        const int r  = t / POOL;
        const int py = t - r * POOL;

        const float4 rv = *reinterpret_cast<const float4*>(rois + (size_t)r * 4);
        const int xmin = (int)rv.x;
        const int xmax = (int)rv.y;
        const int ymin = (int)rv.z;
        const int ymax = (int)rv.w;
        const int sy = ymax - ymin;
        const int sx = xmax - xmin;

        // y coords: uniform for the whole block (reference-exact fp32 ops).
        const float scy  = (float)sy / 7.0f;
        const float srcy = (float)py * scy;
        const int   iy0  = (int)floorf(srcy);
        const int   iy1  = min(iy0 + 1, sy - 1);
        const float fy   = srcy - (float)iy0;
        const size_t rowy0 = (size_t)(ymin + iy0) * FM_W;
        const size_t rowy1 = (size_t)(ymin + iy1) * FM_W;

        const float scx = (float)sx / 7.0f;
        const size_t obase = (size_t)t * POOL * FM_C;   // out[r][py][0][0]

        #pragma unroll
        for (int j = 0; j < 4; ++j) {
            const int px = j * 2 + half;
            if (px < POOL) {
                const float srcx = (float)px * scx;
                const int   ix0  = (int)floorf(srcx);
                const int   ix1  = min(ix0 + 1, sx - 1);
                const float fx   = srcx - (float)ix0;
                const int   x0   = xmin + ix0;
                const int   x1   = xmin + ix1;

                const float4 tl = *reinterpret_cast<const float4*>(fm + (rowy0 + x0) * FM_C + c4);
                const float4 tr = *reinterpret_cast<const float4*>(fm + (rowy0 + x1) * FM_C + c4);
                const float4 bl = *reinterpret_cast<const float4*>(fm + (rowy1 + x0) * FM_C + c4);
                const float4 br = *reinterpret_cast<const float4*>(fm + (rowy1 + x1) * FM_C + c4);

                f32x4 o;
                {
                    float top, bot;
                    top = tl.x + (tr.x - tl.x) * fx; bot = bl.x + (br.x - bl.x) * fx; o.x = top + (bot - top) * fy;
                    top = tl.y + (tr.y - tl.y) * fx; bot = bl.y + (br.y - bl.y) * fx; o.y = top + (bot - top) * fy;
                    top = tl.z + (tr.z - tl.z) * fx; bot = bl.z + (br.z - bl.z) * fx; o.z = top + (bot - top) * fy;
                    top = tl.w + (tr.w - tl.w) * fx; bot = bl.w + (br.w - bl.w) * fx; o.w = top + (bot - top) * fy;
                }

                f32x4* dst = reinterpret_cast<f32x4*>(out + obase + (size_t)px * FM_C + c4);
                __builtin_nontemporal_store(o, dst);
            }
        }
    }
}

// ---------- Fallback: proven R4 kernel (27.5us), used if ws too small ----------
__global__ __launch_bounds__(256) void roi_pool_fallback(
    const float* __restrict__ fm, const float* __restrict__ rois,
    float* __restrict__ out, int n_cells)
{
    const int tid  = threadIdx.x;
    const int g    = blockIdx.x & 7;
    const int cb   = blockIdx.x >> 3;
    const int cell = cb * CELLS_PER_BLK + (tid >> 4);
    if (cell >= n_cells) return;
    const int c4   = (g << 6) + ((tid & 15) << 2);

    const int r  = cell / (POOL * POOL);
    const int p  = cell - r * (POOL * POOL);
    const int py = p / POOL;
    const int px = p - py * POOL;

    const float4 rv = *reinterpret_cast<const float4*>(rois + (size_t)r * 4);
    const int xmin = (int)rv.x, xmax = (int)rv.y, ymin = (int)rv.z, ymax = (int)rv.w;
    const int sy = ymax - ymin, sx = xmax - xmin;

    const float scy = (float)sy / 7.0f, srcy = (float)py * scy;
    const int iy0 = (int)floorf(srcy), iy1 = min(iy0 + 1, sy - 1);
    const float fy = srcy - (float)iy0;
    const int y0 = ymin + iy0, y1 = ymin + iy1;

    const float scx = (float)sx / 7.0f, srcx = (float)px * scx;
    const int ix0 = (int)floorf(srcx), ix1 = min(ix0 + 1, sx - 1);
    const float fx = srcx - (float)ix0;
    const int x0 = xmin + ix0, x1 = xmin + ix1;

    const float4 tl = *reinterpret_cast<const float4*>(fm + ((size_t)(y0 * FM_W + x0)) * FM_C + c4);
    const float4 tr = *reinterpret_cast<const float4*>(fm + ((size_t)(y0 * FM_W + x1)) * FM_C + c4);
    const float4 bl = *reinterpret_cast<const float4*>(fm + ((size_t)(y1 * FM_W + x0)) * FM_C + c4);
    const float4 br = *reinterpret_cast<const float4*>(fm + ((size_t)(y1 * FM_W + x1)) * FM_C + c4);

    f32x4 o;
    float top, bot;
    top = tl.x + (tr.x - tl.x) * fx; bot = bl.x + (br.x - bl.x) * fx; o.x = top + (bot - top) * fy;
    top = tl.y + (tr.y - tl.y) * fx; bot = bl.y + (br.y - bl.y) * fx; o.y = top + (bot - top) * fy;
    top = tl.z + (tr.z - tl.z) * fx; bot = bl.z + (br.z - bl.z) * fx; o.z = top + (bot - top) * fy;
    top = tl.w + (tr.w - tl.w) * fx; bot = bl.w + (br.w - bl.w) * fx; o.w = top + (bot - top) * fy;

    f32x4* dst = reinterpret_cast<f32x4*>(out + (size_t)cell * FM_C + c4);
    __builtin_nontemporal_store(o, dst);
}

extern "C" void kernel_launch(void* const* d_in, const int* in_sizes, int n_in,
                              void* d_out, int out_size, void* d_ws, size_t ws_size,
                              hipStream_t stream) {
    const float* fm   = (const float*)d_in[0];
    const float* rois = (const float*)d_in[1];
    float* out        = (float*)d_out;

    const int R       = in_sizes[1] / 4;
    const int n_tasks = R * POOL;                 // 7168 (roi,py) rows
    const int cap     = n_tasks;                  // per-stripe worst case
    const size_t need = (size_t)NSTRIPE * 4 + (size_t)NSTRIPE * cap * 4;

    if (ws_size < need) {
        const int n_cells = R * POOL * POOL;
        const int cblocks = (n_cells + CELLS_PER_BLK - 1) / CELLS_PER_BLK;
        roi_pool_fallback<<<cblocks * 8, 256, 0, stream>>>(fm, rois, out, n_cells);
        return;
    }

    int* count = (int*)d_ws;                      // [8]
    int* list  = count + NSTRIPE;                 // [8][cap]

    zero_kernel<<<1, 64, 0, stream>>>(count);
    bin_kernel<<<(n_tasks + 255) / 256, 256, 0, stream>>>(rois, count, list, n_tasks, cap);
    pool_stripe_kernel<<<NSTRIPE * BLK_PER_STRIPE, 256, 0, stream>>>(fm, rois, out, count, list, cap);
}

// Round 10
// 31.669 us; speedup vs baseline: 2.9840x; 2.8124x over previous
//
#include <hip/hip_runtime.h>

#define POOL 7
#define FM_H 128
#define FM_W 128
#define FM_C 512
#define NGRP 8                 // channel groups == XCD count; 64 ch = 4 MiB slice
#define CELLS_PER_BLK 16       // 256 threads = 16 cells x 16 lanes x float4

typedef float f32x4 __attribute__((ext_vector_type(4)));

// R4 structure (proven 27.5us): channel-partitioned, XCD-pinned via bid&7.
// Single A/B change vs R4: PLAIN stores instead of nontemporal. NT was never
// isolated on this structure (added in R3 under a different bottleneck); NT
// ships 256B-fragmented per-XCD write chunks straight to fabric, while plain
// stores let L2 write-back merge dirty lines.
__global__ __launch_bounds__(256) void roi_pool_kernel(
    const float* __restrict__ fm,    // [128,128,512] NHWC (batch 1)
    const float* __restrict__ rois,  // [R,4] = xmin,xmax,ymin,ymax (integral floats)
    float* __restrict__ out,         // [R,7,7,512]
    int n_cells)                     // R*49
{
    const int tid  = threadIdx.x;
    const int g    = blockIdx.x & (NGRP - 1);        // channel group -> XCD
    const int cb   = blockIdx.x >> 3;
    const int cell = cb * CELLS_PER_BLK + (tid >> 4);
    if (cell >= n_cells) return;
    const int c4   = (g << 6) + ((tid & 15) << 2);   // g*64 + lane16*4

    const int r  = cell / (POOL * POOL);
    const int p  = cell - r * (POOL * POOL);
    const int py = p / POOL;
    const int px = p - py * POOL;

    // rois are integral values stored as f32; astype(int32) == truncation.
    const float4 rv = *reinterpret_cast<const float4*>(rois + (size_t)r * 4);
    const int xmin = (int)rv.x;
    const int xmax = (int)rv.y;
    const int ymin = (int)rv.z;
    const int ymax = (int)rv.w;
    const int sy = ymax - ymin;
    const int sx = xmax - xmin;

    // _axis_coords, replicated op-for-op in fp32 to match the reference.
    const float scy  = (float)sy / 7.0f;
    const float srcy = (float)py * scy;
    const int   iy0  = (int)floorf(srcy);
    const int   iy1  = min(iy0 + 1, sy - 1);
    const float fy   = srcy - (float)iy0;
    const int   y0   = ymin + iy0;
    const int   y1   = ymin + iy1;

    const float scx  = (float)sx / 7.0f;
    const float srcx = (float)px * scx;
    const int   ix0  = (int)floorf(srcx);
    const int   ix1  = min(ix0 + 1, sx - 1);
    const float fx   = srcx - (float)ix0;
    const int   x0   = xmin + ix0;
    const int   x1   = xmin + ix1;

    const size_t o00 = ((size_t)(y0 * FM_W + x0)) * FM_C + c4;
    const size_t o01 = ((size_t)(y0 * FM_W + x1)) * FM_C + c4;
    const size_t o10 = ((size_t)(y1 * FM_W + x0)) * FM_C + c4;
    const size_t o11 = ((size_t)(y1 * FM_W + x1)) * FM_C + c4;

    const float4 tl = *reinterpret_cast<const float4*>(fm + o00);
    const float4 tr = *reinterpret_cast<const float4*>(fm + o01);
    const float4 bl = *reinterpret_cast<const float4*>(fm + o10);
    const float4 br = *reinterpret_cast<const float4*>(fm + o11);

    f32x4 o;
    {
        float top, bot;
        top = tl.x + (tr.x - tl.x) * fx; bot = bl.x + (br.x - bl.x) * fx; o.x = top + (bot - top) * fy;
        top = tl.y + (tr.y - tl.y) * fx; bot = bl.y + (br.y - bl.y) * fx; o.y = top + (bot - top) * fy;
        top = tl.z + (tr.z - tl.z) * fx; bot = bl.z + (br.z - bl.z) * fx; o.z = top + (bot - top) * fy;
        top = tl.w + (tr.w - tl.w) * fx; bot = bl.w + (br.w - bl.w) * fx; o.w = top + (bot - top) * fy;
    }

    // Plain (L2-allocating, write-back) store — A/B vs R4's nontemporal.
    *reinterpret_cast<f32x4*>(out + (size_t)cell * FM_C + c4) = o;
}

extern "C" void kernel_launch(void* const* d_in, const int* in_sizes, int n_in,
                              void* d_out, int out_size, void* d_ws, size_t ws_size,
                              hipStream_t stream) {
    const float* fm   = (const float*)d_in[0];
    const float* rois = (const float*)d_in[1];
    float* out        = (float*)d_out;

    const int R       = in_sizes[1] / 4;
    const int n_cells = R * POOL * POOL;                                // 50176
    const int cblocks = (n_cells + CELLS_PER_BLK - 1) / CELLS_PER_BLK;  // 3136
    const int blocks  = cblocks * NGRP;                                 // 25088

    roi_pool_kernel<<<blocks, 256, 0, stream>>>(fm, rois, out, n_cells);
}

// Round 11
// 28.202 us; speedup vs baseline: 3.3509x; 1.1229x over previous
//
#include <hip/hip_runtime.h>

#define POOL 7
#define FM_H 128
#define FM_W 128
#define FM_C 512
#define NGRP 8                 // channel groups == XCD count; 64 ch = 4 MiB slice
#define CELLS_PER_BLK 16       // 256 threads = 16 cells x 16 lanes x float4

typedef float f32x4 __attribute__((ext_vector_type(4)));

// FINAL: R4 structure (best measured: 27.5us, ~5.3 TB/s effective mixed BW).
// - Channel-partitioned: group g = blockIdx&7 -> XCD g (empirical round-robin
//   dispatch). Each XCD touches only its 4 MiB channel slice of fm -> no
//   cross-XCD L2 duplication (R1-R3: FETCH 151->~45 MB, 60->27.5us).
// - Nontemporal stores: write-once output must not evict the fm slice
//   (R10 A/B: plain stores regress to 31.7us, NT +15%).
// - Refuted alternatives: smaller slice (R5), L2 pre-warm (R6), persistent
//   grid+ILP (R7), stripe binning for write contiguity (R8/R9).
__global__ __launch_bounds__(256) void roi_pool_kernel(
    const float* __restrict__ fm,    // [128,128,512] NHWC (batch 1)
    const float* __restrict__ rois,  // [R,4] = xmin,xmax,ymin,ymax (integral floats)
    float* __restrict__ out,         // [R,7,7,512]
    int n_cells)                     // R*49
{
    const int tid  = threadIdx.x;
    const int g    = blockIdx.x & (NGRP - 1);        // channel group -> XCD
    const int cb   = blockIdx.x >> 3;
    const int cell = cb * CELLS_PER_BLK + (tid >> 4);
    if (cell >= n_cells) return;
    const int c4   = (g << 6) + ((tid & 15) << 2);   // g*64 + lane16*4

    const int r  = cell / (POOL * POOL);
    const int p  = cell - r * (POOL * POOL);
    const int py = p / POOL;
    const int px = p - py * POOL;

    // rois are integral values stored as f32; astype(int32) == truncation.
    const float4 rv = *reinterpret_cast<const float4*>(rois + (size_t)r * 4);
    const int xmin = (int)rv.x;
    const int xmax = (int)rv.y;
    const int ymin = (int)rv.z;
    const int ymax = (int)rv.w;
    const int sy = ymax - ymin;
    const int sx = xmax - xmin;

    // _axis_coords, replicated op-for-op in fp32 to match the reference.
    const float scy  = (float)sy / 7.0f;
    const float srcy = (float)py * scy;
    const int   iy0  = (int)floorf(srcy);
    const int   iy1  = min(iy0 + 1, sy - 1);
    const float fy   = srcy - (float)iy0;
    const int   y0   = ymin + iy0;
    const int   y1   = ymin + iy1;

    const float scx  = (float)sx / 7.0f;
    const float srcx = (float)px * scx;
    const int   ix0  = (int)floorf(srcx);
    const int   ix1  = min(ix0 + 1, sx - 1);
    const float fx   = srcx - (float)ix0;
    const int   x0   = xmin + ix0;
    const int   x1   = xmin + ix1;

    const size_t o00 = ((size_t)(y0 * FM_W + x0)) * FM_C + c4;
    const size_t o01 = ((size_t)(y0 * FM_W + x1)) * FM_C + c4;
    const size_t o10 = ((size_t)(y1 * FM_W + x0)) * FM_C + c4;
    const size_t o11 = ((size_t)(y1 * FM_W + x1)) * FM_C + c4;

    const float4 tl = *reinterpret_cast<const float4*>(fm + o00);
    const float4 tr = *reinterpret_cast<const float4*>(fm + o01);
    const float4 bl = *reinterpret_cast<const float4*>(fm + o10);
    const float4 br = *reinterpret_cast<const float4*>(fm + o11);

    f32x4 o;
    {
        float top, bot;
        top = tl.x + (tr.x - tl.x) * fx; bot = bl.x + (br.x - bl.x) * fx; o.x = top + (bot - top) * fy;
        top = tl.y + (tr.y - tl.y) * fx; bot = bl.y + (br.y - bl.y) * fx; o.y = top + (bot - top) * fy;
        top = tl.z + (tr.z - tl.z) * fx; bot = bl.z + (br.z - bl.z) * fx; o.z = top + (bot - top) * fy;
        top = tl.w + (tr.w - tl.w) * fx; bot = bl.w + (br.w - bl.w) * fx; o.w = top + (bot - top) * fy;
    }

    // Nontemporal streaming store — keep the write-once output out of L2
    // (R10 A/B: +15% vs plain store).
    f32x4* dst = reinterpret_cast<f32x4*>(out + (size_t)cell * FM_C + c4);
    __builtin_nontemporal_store(o, dst);
}

extern "C" void kernel_launch(void* const* d_in, const int* in_sizes, int n_in,
                              void* d_out, int out_size, void* d_ws, size_t ws_size,
                              hipStream_t stream) {
    const float* fm   = (const float*)d_in[0];
    const float* rois = (const float*)d_in[1];
    float* out        = (float*)d_out;

    const int R       = in_sizes[1] / 4;
    const int n_cells = R * POOL * POOL;                                // 50176
    const int cblocks = (n_cells + CELLS_PER_BLK - 1) / CELLS_PER_BLK;  // 3136
    const int blocks  = cblocks * NGRP;                                 // 25088

    roi_pool_kernel<<<blocks, 256, 0, stream>>>(fm, rois, out, n_cells);
}